// Round 17
// baseline (372.335 us; speedup 1.0000x reference)
//
#include <hip/hip_runtime.h>
#include <hip/hip_cooperative_groups.h>

namespace cg = cooperative_groups;

#define N_B 8
#define DIM 256

constexpr float C2    = 2.8853900817779268f;   // 2*log2(e)
constexpr float LOG2E = 1.4426950408889634f;

typedef __attribute__((ext_vector_type(8))) short short8;
typedef __attribute__((ext_vector_type(4))) float f32x4;
typedef unsigned short ushort_t;

__device__ __forceinline__ unsigned hi2(float a, float b) {
    return (__float_as_uint(a) >> 16) | (__float_as_uint(b) & 0xFFFF0000u);
}
__device__ __forceinline__ float trunc_res(float a) {
    return a - __uint_as_float(__float_as_uint(a) & 0xFFFF0000u);
}

// One fused cooperative kernel: prep -> proj -> scores+softmax -> av
// grid 512 x 256thr (2 blocks/CU), 50KB LDS union, grid.sync between phases.
__global__ __launch_bounds__(256, 2) void fused_all(
    const float* __restrict__ query, const float* __restrict__ key,
    const float* __restrict__ value,
    const float* __restrict__ Wq, const float* __restrict__ Wk,
    const float* __restrict__ Wv, float* __restrict__ out,
    float* __restrict__ EQ, float* __restrict__ EK,
    ushort_t* __restrict__ WqT_hi, ushort_t* __restrict__ WqT_lo,
    ushort_t* __restrict__ WkT_hi, ushort_t* __restrict__ WkT_lo,
    ushort_t* __restrict__ VT_hi,  ushort_t* __restrict__ VT_lo,
    ushort_t* __restrict__ ANh,    ushort_t* __restrict__ ANl)
{
    cg::grid_group grid = cg::this_grid();
    __shared__ __align__(16) char smem[50176];

    int bid = blockIdx.x;
    int tid = threadIdx.x;

    // ---------------- phase 1: prep (transpose + bf16 hi/lo split), blocks 0..159 ----
    if (bid < 160) {
        float (*T)[68] = (float(*)[68])(smem + 32768);
        int id = bid;
        const float* src; ushort_t *dhi, *dlo; int t;
        if (id < 16)      { src = Wq; dhi = WqT_hi; dlo = WqT_lo; t = id; }
        else if (id < 32) { src = Wk; dhi = WkT_hi; dlo = WkT_lo; t = id - 16; }
        else {
            int v = id - 32; int b = v >> 4; t = v & 15;
            src = value + b * DIM * DIM; dhi = VT_hi + b * DIM * DIM; dlo = VT_lo + b * DIM * DIM;
        }
        int R0 = (t >> 2) * 64, C0 = (t & 3) * 64;
        int r = tid >> 2, q = tid & 3;
#pragma unroll
        for (int i = 0; i < 4; ++i)
            *(float4*)&T[r][q * 16 + i * 4] = *(const float4*)&src[(size_t)(R0 + r) * DIM + C0 + q * 16 + i * 4];
        __syncthreads();
        float f[16];
#pragma unroll
        for (int j = 0; j < 16; ++j) f[j] = T[q * 16 + j][r];
        unsigned h[8], l[8];
#pragma unroll
        for (int j = 0; j < 8; ++j) {
            h[j] = hi2(f[2 * j], f[2 * j + 1]);
            l[j] = hi2(trunc_res(f[2 * j]), trunc_res(f[2 * j + 1]));
        }
        size_t base = (size_t)(C0 + r) * DIM + R0 + q * 16;
        *(uint4*)&dhi[base]     = make_uint4(h[0], h[1], h[2], h[3]);
        *(uint4*)&dhi[base + 8] = make_uint4(h[4], h[5], h[6], h[7]);
        *(uint4*)&dlo[base]     = make_uint4(l[0], l[1], l[2], l[3]);
        *(uint4*)&dlo[base + 8] = make_uint4(l[4], l[5], l[6], l[7]);
    }
    __threadfence();
    grid.sync();

    // ---------------- phase 2: proj (MFMA, hi/lo bf16), blocks 0..255 ----
    if (bid < 256) {
        ushort_t* Ah = (ushort_t*)smem;
        ushort_t* Al = (ushort_t*)(smem + 8192);
        ushort_t* Bh = (ushort_t*)(smem + 16384);
        ushort_t* Bl = (ushort_t*)(smem + 24576);
        float (*T)[68] = (float(*)[68])(smem + 32768);

        int y = bid >> 4;
        int b = y >> 1; bool isK = y & 1;
        const float* A = (isK ? key : query) + b * DIM * DIM;
        const ushort_t* BThi = isK ? WkT_hi : WqT_hi;
        const ushort_t* BTlo = isK ? WkT_lo : WqT_lo;

        int x = bid & 15;
        int R0 = (x >> 2) * 64, C0 = (x & 3) * 64;

        int w = tid >> 6, lane = tid & 63;
        int wr = w >> 1, wc = w & 1;
        int l15 = lane & 15, l4 = lane >> 4;
        int sr = tid >> 2, skq = (tid & 3) * 16;

        f32x4 acc[2][2] = {};
        float4 areg0, areg1, areg2, areg3;
        uint4 bh0, bh1, bl0, bl1;
        {
            const float* ap = &A[(size_t)(R0 + sr) * DIM + skq];
            areg0 = *(const float4*)&ap[0];  areg1 = *(const float4*)&ap[4];
            areg2 = *(const float4*)&ap[8];  areg3 = *(const float4*)&ap[12];
            size_t bb = (size_t)(C0 + sr) * DIM + skq;
            bh0 = *(const uint4*)&BThi[bb]; bh1 = *(const uint4*)&BThi[bb + 8];
            bl0 = *(const uint4*)&BTlo[bb]; bl1 = *(const uint4*)&BTlo[bb + 8];
        }

        for (int ks = 0; ks < 4; ++ks) {
            {
                int i0 = (sr * 64 + skq)     ^ ((sr & 7) << 3);
                int i1 = (sr * 64 + skq + 8) ^ ((sr & 7) << 3);
                uint4 hv0 = make_uint4(hi2(areg0.x, areg0.y), hi2(areg0.z, areg0.w),
                                       hi2(areg1.x, areg1.y), hi2(areg1.z, areg1.w));
                uint4 hv1 = make_uint4(hi2(areg2.x, areg2.y), hi2(areg2.z, areg2.w),
                                       hi2(areg3.x, areg3.y), hi2(areg3.z, areg3.w));
                uint4 lv0 = make_uint4(hi2(trunc_res(areg0.x), trunc_res(areg0.y)),
                                       hi2(trunc_res(areg0.z), trunc_res(areg0.w)),
                                       hi2(trunc_res(areg1.x), trunc_res(areg1.y)),
                                       hi2(trunc_res(areg1.z), trunc_res(areg1.w)));
                uint4 lv1 = make_uint4(hi2(trunc_res(areg2.x), trunc_res(areg2.y)),
                                       hi2(trunc_res(areg2.z), trunc_res(areg2.w)),
                                       hi2(trunc_res(areg3.x), trunc_res(areg3.y)),
                                       hi2(trunc_res(areg3.z), trunc_res(areg3.w)));
                *(uint4*)&Ah[i0] = hv0; *(uint4*)&Ah[i1] = hv1;
                *(uint4*)&Al[i0] = lv0; *(uint4*)&Al[i1] = lv1;
                *(uint4*)&Bh[i0] = bh0; *(uint4*)&Bh[i1] = bh1;
                *(uint4*)&Bl[i0] = bl0; *(uint4*)&Bl[i1] = bl1;
            }
            __syncthreads();
            if (ks < 3) {
                int K0 = (ks + 1) * 64;
                const float* ap = &A[(size_t)(R0 + sr) * DIM + K0 + skq];
                areg0 = *(const float4*)&ap[0];  areg1 = *(const float4*)&ap[4];
                areg2 = *(const float4*)&ap[8];  areg3 = *(const float4*)&ap[12];
                size_t bb = (size_t)(C0 + sr) * DIM + K0 + skq;
                bh0 = *(const uint4*)&BThi[bb]; bh1 = *(const uint4*)&BThi[bb + 8];
                bl0 = *(const uint4*)&BTlo[bb]; bl1 = *(const uint4*)&BTlo[bb + 8];
            }
#pragma unroll
            for (int kk = 0; kk < 2; ++kk) {
                int kb = kk * 32 + l4 * 8;
                short8 ah[2], al[2], bh[2], bl[2];
#pragma unroll
                for (int h = 0; h < 2; ++h) {
                    int arow = wr * 32 + h * 16 + l15;
                    int aidx = (arow * 64 + kb) ^ ((arow & 7) << 3);
                    ah[h] = *(const short8*)&Ah[aidx];
                    al[h] = *(const short8*)&Al[aidx];
                    int bcol = wc * 32 + h * 16 + l15;
                    int bidx = (bcol * 64 + kb) ^ ((bcol & 7) << 3);
                    bh[h] = *(const short8*)&Bh[bidx];
                    bl[h] = *(const short8*)&Bl[bidx];
                }
#pragma unroll
                for (int i = 0; i < 2; ++i)
#pragma unroll
                    for (int j = 0; j < 2; ++j) {
                        acc[i][j] = __builtin_amdgcn_mfma_f32_16x16x32_bf16(ah[i], bh[j], acc[i][j], 0, 0, 0);
                        acc[i][j] = __builtin_amdgcn_mfma_f32_16x16x32_bf16(ah[i], bl[j], acc[i][j], 0, 0, 0);
                        acc[i][j] = __builtin_amdgcn_mfma_f32_16x16x32_bf16(al[i], bh[j], acc[i][j], 0, 0, 0);
                    }
            }
            __syncthreads();
        }

#pragma unroll
        for (int i = 0; i < 2; ++i)
#pragma unroll
            for (int j = 0; j < 2; ++j) {
                float ev[4];
#pragma unroll
                for (int v = 0; v < 4; ++v) ev[v] = __builtin_amdgcn_exp2f(C2 * acc[i][j][v]);
                int row = wr * 32 + i * 16 + l4 * 4;
                int col = wc * 32 + j * 16 + l15;
                if (isK) {
#pragma unroll
                    for (int v = 0; v < 4; ++v) T[row + v][col] = ev[v];
                } else {
                    *(float4*)&T[col][row] = make_float4(ev[0], ev[1], ev[2], ev[3]);
                }
            }
        __syncthreads();
        {
            int r = tid >> 2, q = tid & 3;
            float* dst = isK ? &EK[(size_t)b * DIM * DIM + (size_t)(R0 + r) * DIM + C0 + q * 16]
                             : &EQ[(size_t)b * DIM * DIM + (size_t)(C0 + r) * DIM + R0 + q * 16];
#pragma unroll
            for (int i = 0; i < 4; ++i)
                *(float4*)&dst[i * 4] = *(const float4*)&T[r][q * 16 + i * 4];
        }
    }
    __threadfence();
    grid.sync();

    // ---------------- phase 3: scores + softmax(axis=n) -> attn hi/lo [n][m], all blocks ----
    {
        float (*Eks)[DIM] = (float(*)[DIM])smem;                 // 4 KB
        float* Ws = (float*)(smem + 4096);                       // 1 KB
        float (*part)[64][16] = (float(*)[64][16])(smem + 5120); // 12 KB

        int b  = bid >> 6;
        int M0 = (bid & 63) * 4;
        const float* Qb = EQ + b * DIM * DIM;   // [h][n]
        const float* Kb = EK + b * DIM * DIM;   // [m][h]

        int hs = tid >> 6, lane = tid & 63;
        int n0 = lane * 4;

        {
            int row = tid >> 6, h4 = (tid & 63) * 4;
            *(float4*)&Eks[row][h4] = *(const float4*)&Kb[(M0 + row) * DIM + h4];
        }
        if (tid < 64) *(float4*)&Ws[tid * 4] = *(const float4*)&Wv[tid * 4];

        float wsum = Wv[lane] + Wv[lane + 64] + Wv[lane + 128] + Wv[lane + 192];
#pragma unroll
        for (int o = 32; o; o >>= 1) wsum += __shfl_xor(wsum, o);
        __syncthreads();

        float acc[4][4] = {};
        const float* qbase = Qb + (hs * 4) * 256 + n0;

#pragma unroll 2
        for (int c = 0; c < 16; ++c) {
            float4 wv4 = *(const float4*)&Ws[c * 16 + hs * 4];
            float wva[4] = {wv4.x, wv4.y, wv4.z, wv4.w};
            float eka[4][4];
#pragma unroll
            for (int i = 0; i < 4; ++i) {
                float4 e4 = *(const float4*)&Eks[i][c * 16 + hs * 4];
                eka[i][0] = e4.x; eka[i][1] = e4.y; eka[i][2] = e4.z; eka[i][3] = e4.w;
            }
            const float* qc = qbase + c * 16 * 256;
#pragma unroll
            for (int hh = 0; hh < 2; ++hh) {
                float4 q0 = *(const float4*)&qc[(hh * 2) * 256];
                float4 q1 = *(const float4*)&qc[(hh * 2 + 1) * 256];
                float q0a[4] = {q0.x, q0.y, q0.z, q0.w};
                float q1a[4] = {q1.x, q1.y, q1.z, q1.w};
                float w0 = wva[hh * 2], w1 = wva[hh * 2 + 1];
#pragma unroll
                for (int i = 0; i < 4; ++i) {
                    float e0 = eka[i][hh * 2], e1 = eka[i][hh * 2 + 1];
#pragma unroll
                    for (int j = 0; j < 4; ++j) {
                        float d0 = fmaf(q0a[j], e0, 1.0f);
                        float d1 = fmaf(q1a[j], e1, 1.0f);
                        float num = fmaf(w0, d1, w1 * d0);
                        acc[i][j] = fmaf(num, __builtin_amdgcn_rcpf(d0 * d1), acc[i][j]);
                    }
                }
            }
        }

        if (hs) {
#pragma unroll
            for (int i = 0; i < 4; ++i) {
                float4 v = make_float4(acc[i][0], acc[i][1], acc[i][2], acc[i][3]);
                *(float4*)&part[hs - 1][lane][i * 4] = v;
            }
        }
        __syncthreads();
        if (hs == 0) {
#pragma unroll
            for (int p = 0; p < 3; ++p)
#pragma unroll
                for (int i = 0; i < 4; ++i) {
                    float4 v = *(const float4*)&part[p][lane][i * 4];
                    acc[i][0] += v.x; acc[i][1] += v.y; acc[i][2] += v.z; acc[i][3] += v.w;
                }
            float e[4][4], t[4], ri[4];
#pragma unroll
            for (int i = 0; i < 4; ++i) {
                t[i] = 0.0f;
#pragma unroll
                for (int j = 0; j < 4; ++j) {
                    e[i][j] = __builtin_amdgcn_exp2f((wsum - 2.0f * acc[i][j]) * LOG2E);
                    t[i] += e[i][j];
                }
            }
#pragma unroll
            for (int o = 32; o; o >>= 1)
#pragma unroll
                for (int i = 0; i < 4; ++i) t[i] += __shfl_xor(t[i], o);
#pragma unroll
            for (int i = 0; i < 4; ++i) ri[i] = __builtin_amdgcn_rcpf(t[i]);
#pragma unroll
            for (int j = 0; j < 4; ++j) {
                float a0 = e[0][j] * ri[0], a1 = e[1][j] * ri[1];
                float a2 = e[2][j] * ri[2], a3 = e[3][j] * ri[3];
                size_t base = ((size_t)b * DIM + n0 + j) * DIM + M0;
                *(uint2*)&ANh[base] = make_uint2(hi2(a0, a1), hi2(a2, a3));
                *(uint2*)&ANl[base] = make_uint2(hi2(trunc_res(a0), trunc_res(a1)),
                                                 hi2(trunc_res(a2), trunc_res(a3)));
            }
        }
    }
    __threadfence();
    grid.sync();

    // ---------------- phase 4: av (MFMA), blocks 0..127 ----
    if (bid < 128) {
        ushort_t* Ah = (ushort_t*)smem;
        ushort_t* Al = (ushort_t*)(smem + 8192);
        ushort_t* Bh = (ushort_t*)(smem + 16384);
        ushort_t* Bl = (ushort_t*)(smem + 24576);
        float (*T)[68] = (float(*)[68])(smem + 32768);

        int b = bid >> 4;
        int x = bid & 15;
        int R0 = (x >> 2) * 64, C0 = (x & 3) * 64;
        const ushort_t* Abh = ANh + (size_t)b * DIM * DIM;
        const ushort_t* Abl = ANl + (size_t)b * DIM * DIM;
        const ushort_t* Bbh = VT_hi + (size_t)b * DIM * DIM;
        const ushort_t* Bbl = VT_lo + (size_t)b * DIM * DIM;

        int w = tid >> 6, lane = tid & 63;
        int wr = w >> 1, wc = w & 1;
        int l15 = lane & 15, l4 = lane >> 4;
        int sr = tid >> 2, skq = (tid & 3) * 16;

        f32x4 acc[2][2] = {};
        uint4 ah0, ah1, al0, al1, bh0, bh1, bl0, bl1;
        {
            size_t aa = (size_t)(R0 + sr) * DIM + skq;
            size_t bb = (size_t)(C0 + sr) * DIM + skq;
            ah0 = *(const uint4*)&Abh[aa]; ah1 = *(const uint4*)&Abh[aa + 8];
            al0 = *(const uint4*)&Abl[aa]; al1 = *(const uint4*)&Abl[aa + 8];
            bh0 = *(const uint4*)&Bbh[bb]; bh1 = *(const uint4*)&Bbh[bb + 8];
            bl0 = *(const uint4*)&Bbl[bb]; bl1 = *(const uint4*)&Bbl[bb + 8];
        }

        for (int ks = 0; ks < 4; ++ks) {
            {
                int i0 = (sr * 64 + skq)     ^ ((sr & 7) << 3);
                int i1 = (sr * 64 + skq + 8) ^ ((sr & 7) << 3);
                *(uint4*)&Ah[i0] = ah0; *(uint4*)&Ah[i1] = ah1;
                *(uint4*)&Al[i0] = al0; *(uint4*)&Al[i1] = al1;
                *(uint4*)&Bh[i0] = bh0; *(uint4*)&Bh[i1] = bh1;
                *(uint4*)&Bl[i0] = bl0; *(uint4*)&Bl[i1] = bl1;
            }
            __syncthreads();
            if (ks < 3) {
                int K0 = (ks + 1) * 64;
                size_t aa = (size_t)(R0 + sr) * DIM + K0 + skq;
                size_t bb = (size_t)(C0 + sr) * DIM + K0 + skq;
                ah0 = *(const uint4*)&Abh[aa]; ah1 = *(const uint4*)&Abh[aa + 8];
                al0 = *(const uint4*)&Abl[aa]; al1 = *(const uint4*)&Abl[aa + 8];
                bh0 = *(const uint4*)&Bbh[bb]; bh1 = *(const uint4*)&Bbh[bb + 8];
                bl0 = *(const uint4*)&Bbl[bb]; bl1 = *(const uint4*)&Bbl[bb + 8];
            }
#pragma unroll
            for (int kk = 0; kk < 2; ++kk) {
                int kb = kk * 32 + l4 * 8;
                short8 ah[2], al[2], bh[2], bl[2];
#pragma unroll
                for (int h = 0; h < 2; ++h) {
                    int arow = wr * 32 + h * 16 + l15;
                    int aidx = (arow * 64 + kb) ^ ((arow & 7) << 3);
                    ah[h] = *(const short8*)&Ah[aidx];
                    al[h] = *(const short8*)&Al[aidx];
                    int bcol = wc * 32 + h * 16 + l15;
                    int bidx = (bcol * 64 + kb) ^ ((bcol & 7) << 3);
                    bh[h] = *(const short8*)&Bh[bidx];
                    bl[h] = *(const short8*)&Bl[bidx];
                }
#pragma unroll
                for (int i = 0; i < 2; ++i)
#pragma unroll
                    for (int j = 0; j < 2; ++j) {
                        acc[i][j] = __builtin_amdgcn_mfma_f32_16x16x32_bf16(ah[i], bh[j], acc[i][j], 0, 0, 0);
                        acc[i][j] = __builtin_amdgcn_mfma_f32_16x16x32_bf16(ah[i], bl[j], acc[i][j], 0, 0, 0);
                        acc[i][j] = __builtin_amdgcn_mfma_f32_16x16x32_bf16(al[i], bh[j], acc[i][j], 0, 0, 0);
                    }
            }
            __syncthreads();
        }

#pragma unroll
        for (int i = 0; i < 2; ++i)
#pragma unroll
            for (int j = 0; j < 2; ++j) {
                int row = wr * 32 + i * 16 + l4 * 4;
                int col = wc * 32 + j * 16 + l15;
#pragma unroll
                for (int v = 0; v < 4; ++v) T[row + v][col] = acc[i][j][v];
            }
        __syncthreads();
        {
            int r = tid >> 2, q = tid & 3;
            float* dst = &out[((size_t)b * DIM + R0 + r) * DIM + C0 + q * 16];
#pragma unroll
            for (int i = 0; i < 4; ++i)
                *(float4*)&dst[i * 4] = *(const float4*)&T[r][q * 16 + i * 4];
        }
    }
}

extern "C" void kernel_launch(void* const* d_in, const int* in_sizes, int n_in,
                              void* d_out, int out_size, void* d_ws, size_t ws_size,
                              hipStream_t stream)
{
    const float* query = (const float*)d_in[0];
    const float* key   = (const float*)d_in[1];
    const float* value = (const float*)d_in[2];
    const float* Wq    = (const float*)d_in[3];
    const float* Wk    = (const float*)d_in[4];
    const float* Wv    = (const float*)d_in[5];
    float* out = (float*)d_out;

    float* EQ = (float*)d_ws;                     // [8][h][n] fp32
    float* EK = EQ + N_B * DIM * DIM;             // [8][m][h] fp32
    ushort_t* us = (ushort_t*)(EK + N_B * DIM * DIM);
    ushort_t* WqT_hi = us; us += DIM * DIM;
    ushort_t* WqT_lo = us; us += DIM * DIM;
    ushort_t* WkT_hi = us; us += DIM * DIM;
    ushort_t* WkT_lo = us; us += DIM * DIM;
    ushort_t* VT_hi  = us; us += N_B * DIM * DIM;
    ushort_t* VT_lo  = us; us += N_B * DIM * DIM;
    ushort_t* ANh    = us; us += N_B * DIM * DIM;
    ushort_t* ANl    = us; us += N_B * DIM * DIM;

    void* args[] = {
        (void*)&query, (void*)&key, (void*)&value,
        (void*)&Wq, (void*)&Wk, (void*)&Wv, (void*)&out,
        (void*)&EQ, (void*)&EK,
        (void*)&WqT_hi, (void*)&WqT_lo, (void*)&WkT_hi, (void*)&WkT_lo,
        (void*)&VT_hi, (void*)&VT_lo, (void*)&ANh, (void*)&ANl
    };
    hipLaunchCooperativeKernel((void*)fused_all, dim3(512), dim3(256),
                               args, 0, stream);
}

// Round 18
// 40.189 us; speedup vs baseline: 9.2646x; 9.2646x over previous
//
#include <hip/hip_runtime.h>

#define N_B 8
#define DIM 256

constexpr float C2    = 2.8853900817779268f;   // 2*log2(e)
constexpr float LOG2E = 1.4426950408889634f;

typedef __attribute__((ext_vector_type(8))) short short8;
typedef __attribute__((ext_vector_type(4))) float f32x4;
typedef unsigned short ushort_t;

__device__ __forceinline__ unsigned hi2(float a, float b) {
    return (__float_as_uint(a) >> 16) | (__float_as_uint(b) & 0xFFFF0000u);
}
__device__ __forceinline__ float trunc_res(float a) {
    return a - __uint_as_float(__float_as_uint(a) & 0xFFFF0000u);
}

// ---------------- proj (MFMA, 512 thr = 8 waves, in-kernel W transpose) ----------------
// 64x64 tile; wave (wr,wc) of 2x4 owns rows [wr*32,+32) x cols [wc*16,+16).
__global__ __launch_bounds__(512) void proj_mfma(
    const float* __restrict__ query, const float* __restrict__ key,
    const float* __restrict__ Wq, const float* __restrict__ Wk,
    float* __restrict__ EQ, float* __restrict__ EK)
{
    __shared__ __align__(16) ushort_t Ah[64 * 64], Al[64 * 64], Bh[64 * 64], Bl[64 * 64];
    __shared__ __align__(16) float T[64][68];

    int y = blockIdx.y;
    int b = y >> 1; bool isK = y & 1;
    const float* A    = (isK ? key : query) + b * DIM * DIM;
    const float* Wsrc = isK ? Wk : Wq;

    int x = blockIdx.x;
    int R0 = (x >> 2) * 64, C0 = (x & 3) * 64;

    int tid = threadIdx.x;
    int w = tid >> 6, lane = tid & 63;
    int wr = w >> 2, wc = w & 3;
    int l15 = lane & 15, l4 = lane >> 4;

    int sr = tid >> 3, skq = (tid & 7) * 8;      // A staging: row 0..63, k-octet
    int kp = tid & 31, cg = tid >> 5;            // B staging: k-pair, col-quad (cg 0..15)

    f32x4 acc[2] = {};
    float4 areg0, areg1;
    float4 w00, w10;

    {   // prologue stage-0 loads
        const float* ap = &A[(size_t)(R0 + sr) * DIM + skq];
        areg0 = *(const float4*)&ap[0];  areg1 = *(const float4*)&ap[4];
        const float* wp0 = &Wsrc[(size_t)(2 * kp)     * DIM + C0 + cg * 4];
        const float* wp1 = &Wsrc[(size_t)(2 * kp + 1) * DIM + C0 + cg * 4];
        w00 = *(const float4*)&wp0[0];
        w10 = *(const float4*)&wp1[0];
    }

    for (int ks = 0; ks < 4; ++ks) {
        {
            int i0 = (sr * 64 + skq) ^ ((sr & 7) << 3);
            uint4 hv = make_uint4(hi2(areg0.x, areg0.y), hi2(areg0.z, areg0.w),
                                  hi2(areg1.x, areg1.y), hi2(areg1.z, areg1.w));
            uint4 lv = make_uint4(hi2(trunc_res(areg0.x), trunc_res(areg0.y)),
                                  hi2(trunc_res(areg0.z), trunc_res(areg0.w)),
                                  hi2(trunc_res(areg1.x), trunc_res(areg1.y)),
                                  hi2(trunc_res(areg1.z), trunc_res(areg1.w)));
            *(uint4*)&Ah[i0] = hv;
            *(uint4*)&Al[i0] = lv;
            float a0[4] = {w00.x, w00.y, w00.z, w00.w};
            float a1[4] = {w10.x, w10.y, w10.z, w10.w};
#pragma unroll
            for (int c = 0; c < 4; ++c) {
                int col = cg * 4 + c;
                int idx = (col * 64 + 2 * kp) ^ ((col & 7) << 3);
                *(unsigned*)&Bh[idx] = hi2(a0[c], a1[c]);
                *(unsigned*)&Bl[idx] = hi2(trunc_res(a0[c]), trunc_res(a1[c]));
            }
        }
        __syncthreads();
        if (ks < 3) {
            int K0 = (ks + 1) * 64;
            const float* ap = &A[(size_t)(R0 + sr) * DIM + K0 + skq];
            areg0 = *(const float4*)&ap[0];  areg1 = *(const float4*)&ap[4];
            const float* wp0 = &Wsrc[(size_t)(K0 + 2 * kp)     * DIM + C0 + cg * 4];
            const float* wp1 = &Wsrc[(size_t)(K0 + 2 * kp + 1) * DIM + C0 + cg * 4];
            w00 = *(const float4*)&wp0[0];
            w10 = *(const float4*)&wp1[0];
        }
#pragma unroll
        for (int kk = 0; kk < 2; ++kk) {
            int kb = kk * 32 + l4 * 8;
            short8 ah[2], al[2], bh, bl;
#pragma unroll
            for (int i = 0; i < 2; ++i) {
                int arow = wr * 32 + i * 16 + l15;
                int aidx = (arow * 64 + kb) ^ ((arow & 7) << 3);
                ah[i] = *(const short8*)&Ah[aidx];
                al[i] = *(const short8*)&Al[aidx];
            }
            {
                int bcol = wc * 16 + l15;
                int bidx = (bcol * 64 + kb) ^ ((bcol & 7) << 3);
                bh = *(const short8*)&Bh[bidx];
                bl = *(const short8*)&Bl[bidx];
            }
#pragma unroll
            for (int i = 0; i < 2; ++i) {
                acc[i] = __builtin_amdgcn_mfma_f32_16x16x32_bf16(ah[i], bh, acc[i], 0, 0, 0);
                acc[i] = __builtin_amdgcn_mfma_f32_16x16x32_bf16(ah[i], bl, acc[i], 0, 0, 0);
                acc[i] = __builtin_amdgcn_mfma_f32_16x16x32_bf16(al[i], bh, acc[i], 0, 0, 0);
            }
        }
        __syncthreads();
    }

    // epilogue: exp2, bounce-transpose, coalesced writes
#pragma unroll
    for (int i = 0; i < 2; ++i) {
        float ev[4];
#pragma unroll
        for (int v = 0; v < 4; ++v) ev[v] = __builtin_amdgcn_exp2f(C2 * acc[i][v]);
        int row = wr * 32 + i * 16 + l4 * 4;
        int col = wc * 16 + l15;
        if (isK) {
#pragma unroll
            for (int v = 0; v < 4; ++v) T[row + v][col] = ev[v];
        } else {
            *(float4*)&T[col][row] = make_float4(ev[0], ev[1], ev[2], ev[3]);
        }
    }
    __syncthreads();
    {
        int r = tid >> 3, q = tid & 7;
        float* dst = isK ? &EK[(size_t)b * DIM * DIM + (size_t)(R0 + r) * DIM + C0 + q * 8]
                         : &EQ[(size_t)b * DIM * DIM + (size_t)(C0 + r) * DIM + R0 + q * 8];
        *(float4*)&dst[0] = *(const float4*)&T[r][q * 8];
        *(float4*)&dst[4] = *(const float4*)&T[r][q * 8 + 4];
    }
}

// ---------------- fused scores + softmax(axis=n) -> attnN hi/lo bf16 [n][m] ----------------
// Barrier-free main loop + q-prefetch one chunk ahead (registers).
__global__ __launch_bounds__(256, 2) void scores_softmax_kernel(
    const float* __restrict__ EQ, const float* __restrict__ EK,
    const float* __restrict__ Wv,
    ushort_t* __restrict__ ANh, ushort_t* __restrict__ ANl)
{
    int b  = blockIdx.y;
    int M0 = blockIdx.x * 4;
    const float* Qb = EQ + b * DIM * DIM;   // [h][n]
    const float* Kb = EK + b * DIM * DIM;   // [m][h]

    __shared__ __align__(16) float Eks[4][DIM];
    __shared__ __align__(16) float Ws[DIM];
    __shared__ __align__(16) float part[3][64][16];

    int tid  = threadIdx.x;
    int hs = tid >> 6, lane = tid & 63;
    int n0 = lane * 4;

    {
        int row = tid >> 6, h4 = (tid & 63) * 4;
        *(float4*)&Eks[row][h4] = *(const float4*)&Kb[(M0 + row) * DIM + h4];
    }
    if (tid < 64) *(float4*)&Ws[tid * 4] = *(const float4*)&Wv[tid * 4];

    float wsum = Wv[lane] + Wv[lane + 64] + Wv[lane + 128] + Wv[lane + 192];
#pragma unroll
    for (int o = 32; o; o >>= 1) wsum += __shfl_xor(wsum, o);
    __syncthreads();

    float acc[4][4] = {};
    const float* qbase = Qb + (hs * 4) * 256 + n0;

    float4 qr[4];
#pragma unroll
    for (int r = 0; r < 4; ++r) qr[r] = *(const float4*)&qbase[r * 256];

    for (int c = 0; c < 16; ++c) {
        float4 qn[4];
        if (c < 15) {
            const float* qc = qbase + (c + 1) * 4096;
#pragma unroll
            for (int r = 0; r < 4; ++r) qn[r] = *(const float4*)&qc[r * 256];
        }
        float4 wv4 = *(const float4*)&Ws[c * 16 + hs * 4];
        float wva[4] = {wv4.x, wv4.y, wv4.z, wv4.w};
        float eka[4][4];
#pragma unroll
        for (int i = 0; i < 4; ++i) {
            float4 e4 = *(const float4*)&Eks[i][c * 16 + hs * 4];
            eka[i][0] = e4.x; eka[i][1] = e4.y; eka[i][2] = e4.z; eka[i][3] = e4.w;
        }
#pragma unroll
        for (int hh = 0; hh < 2; ++hh) {
            float q0a[4] = {qr[hh * 2].x, qr[hh * 2].y, qr[hh * 2].z, qr[hh * 2].w};
            float q1a[4] = {qr[hh * 2 + 1].x, qr[hh * 2 + 1].y, qr[hh * 2 + 1].z, qr[hh * 2 + 1].w};
            float w0 = wva[hh * 2], w1 = wva[hh * 2 + 1];
#pragma unroll
            for (int i = 0; i < 4; ++i) {
                float e0 = eka[i][hh * 2], e1 = eka[i][hh * 2 + 1];
#pragma unroll
                for (int j = 0; j < 4; ++j) {
                    float d0 = fmaf(q0a[j], e0, 1.0f);
                    float d1 = fmaf(q1a[j], e1, 1.0f);
                    float num = fmaf(w0, d1, w1 * d0);
                    acc[i][j] = fmaf(num, __builtin_amdgcn_rcpf(d0 * d1), acc[i][j]);
                }
            }
        }
        if (c < 15) {
#pragma unroll
            for (int r = 0; r < 4; ++r) qr[r] = qn[r];
        }
    }

    if (hs) {
#pragma unroll
        for (int i = 0; i < 4; ++i) {
            float4 v = make_float4(acc[i][0], acc[i][1], acc[i][2], acc[i][3]);
            *(float4*)&part[hs - 1][lane][i * 4] = v;
        }
    }
    __syncthreads();
    if (hs == 0) {
#pragma unroll
        for (int p = 0; p < 3; ++p)
#pragma unroll
            for (int i = 0; i < 4; ++i) {
                float4 v = *(const float4*)&part[p][lane][i * 4];
                acc[i][0] += v.x; acc[i][1] += v.y; acc[i][2] += v.z; acc[i][3] += v.w;
            }
        float e[4][4], t[4], ri[4];
#pragma unroll
        for (int i = 0; i < 4; ++i) {
            t[i] = 0.0f;
#pragma unroll
            for (int j = 0; j < 4; ++j) {
                e[i][j] = __builtin_amdgcn_exp2f((wsum - 2.0f * acc[i][j]) * LOG2E);
                t[i] += e[i][j];
            }
        }
#pragma unroll
        for (int o = 32; o; o >>= 1)
#pragma unroll
            for (int i = 0; i < 4; ++i) t[i] += __shfl_xor(t[i], o);
#pragma unroll
        for (int i = 0; i < 4; ++i) ri[i] = __builtin_amdgcn_rcpf(t[i]);
#pragma unroll
        for (int j = 0; j < 4; ++j) {
            float a0 = e[0][j] * ri[0], a1 = e[1][j] * ri[1];
            float a2 = e[2][j] * ri[2], a3 = e[3][j] * ri[3];
            size_t base = ((size_t)b * DIM + n0 + j) * DIM + M0;
            *(uint2*)&ANh[base] = make_uint2(hi2(a0, a1), hi2(a2, a3));
            *(uint2*)&ANl[base] = make_uint2(hi2(trunc_res(a0), trunc_res(a1)),
                                             hi2(trunc_res(a2), trunc_res(a3)));
        }
    }
}

// ---------------- av (MFMA): 32(n)x64(d) tiles, 256 blocks (full GPU) ----------------
__global__ __launch_bounds__(256) void av_mfma(
    const ushort_t* __restrict__ ANh, const ushort_t* __restrict__ ANl,
    const float* __restrict__ value, float* __restrict__ out)
{
    __shared__ __align__(16) ushort_t Ah[32 * 64], Al[32 * 64], Bh[64 * 64], Bl[64 * 64];
    __shared__ __align__(16) float T[32][68];

    int b = blockIdx.y;
    int x = blockIdx.x;                      // 0..31
    int R0 = (x >> 2) * 32, C0 = (x & 3) * 64;   // n-tile (8), d-tile (4)
    const ushort_t* Abh = ANh + (size_t)b * DIM * DIM;
    const ushort_t* Abl = ANl + (size_t)b * DIM * DIM;
    const float*    Vb  = value + (size_t)b * DIM * DIM;

    int tid = threadIdx.x;
    int w = tid >> 6, lane = tid & 63;
    int wr = w >> 1, wc = w & 1;             // rows wr*16, cols wc*32
    int l15 = lane & 15, l4 = lane >> 4;
    int sr = tid >> 3, skq = (tid & 7) * 8;  // A staging: row 0..31, m-octet
    int kp = tid & 31, cg = tid >> 5;        // V staging: m-pair, d-octet

    f32x4 acc[2] = {};
    uint4 ah0, al0;
    float4 v00, v01, v10, v11;
    {
        size_t aa = (size_t)(R0 + sr) * DIM + skq;
        ah0 = *(const uint4*)&Abh[aa];
        al0 = *(const uint4*)&Abl[aa];
        const float* vp0 = &Vb[(size_t)(2 * kp)     * DIM + C0 + cg * 8];
        const float* vp1 = &Vb[(size_t)(2 * kp + 1) * DIM + C0 + cg * 8];
        v00 = *(const float4*)&vp0[0]; v01 = *(const float4*)&vp0[4];
        v10 = *(const float4*)&vp1[0]; v11 = *(const float4*)&vp1[4];
    }

    for (int ks = 0; ks < 4; ++ks) {
        {
            int i0 = (sr * 64 + skq) ^ ((sr & 7) << 3);
            *(uint4*)&Ah[i0] = ah0;
            *(uint4*)&Al[i0] = al0;
            float a0[8] = {v00.x, v00.y, v00.z, v00.w, v01.x, v01.y, v01.z, v01.w};
            float a1[8] = {v10.x, v10.y, v10.z, v10.w, v11.x, v11.y, v11.z, v11.w};
#pragma unroll
            for (int c = 0; c < 8; ++c) {
                int col = cg * 8 + c;
                int idx = (col * 64 + 2 * kp) ^ ((col & 7) << 3);
                *(unsigned*)&Bh[idx] = hi2(a0[c], a1[c]);
                *(unsigned*)&Bl[idx] = hi2(trunc_res(a0[c]), trunc_res(a1[c]));
            }
        }
        __syncthreads();
        if (ks < 3) {
            int K0 = (ks + 1) * 64;
            size_t aa = (size_t)(R0 + sr) * DIM + K0 + skq;
            ah0 = *(const uint4*)&Abh[aa];
            al0 = *(const uint4*)&Abl[aa];
            const float* vp0 = &Vb[(size_t)(K0 + 2 * kp)     * DIM + C0 + cg * 8];
            const float* vp1 = &Vb[(size_t)(K0 + 2 * kp + 1) * DIM + C0 + cg * 8];
            v00 = *(const float4*)&vp0[0]; v01 = *(const float4*)&vp0[4];
            v10 = *(const float4*)&vp1[0]; v11 = *(const float4*)&vp1[4];
        }
#pragma unroll
        for (int kk = 0; kk < 2; ++kk) {
            int kb = kk * 32 + l4 * 8;
            short8 ah, al, bh[2], bl[2];
            {
                int arow = wr * 16 + l15;
                int aidx = (arow * 64 + kb) ^ ((arow & 7) << 3);
                ah = *(const short8*)&Ah[aidx];
                al = *(const short8*)&Al[aidx];
            }
#pragma unroll
            for (int j = 0; j < 2; ++j) {
                int bcol = wc * 32 + j * 16 + l15;
                int bidx = (bcol * 64 + kb) ^ ((bcol & 7) << 3);
                bh[j] = *(const short8*)&Bh[bidx];
                bl[j] = *(const short8*)&Bl[bidx];
            }
#pragma unroll
            for (int j = 0; j < 2; ++j) {
                acc[j] = __builtin_amdgcn_mfma_f32_16x16x32_bf16(ah, bh[j], acc[j], 0, 0, 0);
                acc[j] = __builtin_amdgcn_mfma_f32_16x16x32_bf16(ah, bl[j], acc[j], 0, 0, 0);
                acc[j] = __builtin_amdgcn_mfma_f32_16x16x32_bf16(al, bh[j], acc[j], 0, 0, 0);
            }
        }
        __syncthreads();
    }

#pragma unroll
    for (int j = 0; j < 2; ++j) {
        int row = wr * 16 + l4 * 4;
        int col = wc * 32 + j * 16 + l15;
#pragma unroll
        for (int v = 0; v < 4; ++v) T[row + v][col] = acc[j][v];
    }
    __syncthreads();
    {
        int r = tid >> 3, q = tid & 7;       // r 0..31, q 0..7
        float* dst = &out[((size_t)b * DIM + R0 + r) * DIM + C0 + q * 8];
        *(float4*)&dst[0] = *(const float4*)&T[r][q * 8];
        *(float4*)&dst[4] = *(const float4*)&T[r][q * 8 + 4];
    }
}

extern "C" void kernel_launch(void* const* d_in, const int* in_sizes, int n_in,
                              void* d_out, int out_size, void* d_ws, size_t ws_size,
                              hipStream_t stream)
{
    const float* query = (const float*)d_in[0];
    const float* key   = (const float*)d_in[1];
    const float* value = (const float*)d_in[2];
    const float* Wq    = (const float*)d_in[3];
    const float* Wk    = (const float*)d_in[4];
    const float* Wv    = (const float*)d_in[5];
    float* out = (float*)d_out;

    float* EQ = (float*)d_ws;
    float* EK = EQ + N_B * DIM * DIM;
    ushort_t* us = (ushort_t*)(EK + N_B * DIM * DIM);
    ushort_t* ANh = us; us += N_B * DIM * DIM;
    ushort_t* ANl = us; us += N_B * DIM * DIM;

    proj_mfma            <<<dim3(16, 16), 512, 0, stream>>>(query, key, Wq, Wk, EQ, EK);
    scores_softmax_kernel<<<dim3(64, 8),  256, 0, stream>>>(EQ, EK, Wv, ANh, ANl);
    av_mfma              <<<dim3(32, 8),  256, 0, stream>>>(ANh, ANl, value, out);
}

// Round 19
// 38.553 us; speedup vs baseline: 9.6577x; 1.0424x over previous
//
#include <hip/hip_runtime.h>

#define N_B 8
#define DIM 256

constexpr float C2    = 2.8853900817779268f;   // 2*log2(e)
constexpr float LOG2E = 1.4426950408889634f;

typedef __attribute__((ext_vector_type(8))) short short8;
typedef __attribute__((ext_vector_type(4))) float f32x4;
typedef unsigned short ushort_t;

__device__ __forceinline__ unsigned hi2(float a, float b) {
    return (__float_as_uint(a) >> 16) | (__float_as_uint(b) & 0xFFFF0000u);
}
__device__ __forceinline__ float trunc_res(float a) {
    return a - __uint_as_float(__float_as_uint(a) & 0xFFFF0000u);
}

// ---------------- proj (MFMA, 512 thr = 8 waves, in-kernel W transpose) ----------------
__global__ __launch_bounds__(512) void proj_mfma(
    const float* __restrict__ query, const float* __restrict__ key,
    const float* __restrict__ Wq, const float* __restrict__ Wk,
    float* __restrict__ EQ, float* __restrict__ EK)
{
    __shared__ __align__(16) ushort_t Ah[64 * 64], Al[64 * 64], Bh[64 * 64], Bl[64 * 64];
    __shared__ __align__(16) float T[64][68];

    int y = blockIdx.y;
    int b = y >> 1; bool isK = y & 1;
    const float* A    = (isK ? key : query) + b * DIM * DIM;
    const float* Wsrc = isK ? Wk : Wq;

    int x = blockIdx.x;
    int R0 = (x >> 2) * 64, C0 = (x & 3) * 64;

    int tid = threadIdx.x;
    int w = tid >> 6, lane = tid & 63;
    int wr = w >> 2, wc = w & 3;
    int l15 = lane & 15, l4 = lane >> 4;

    int sr = tid >> 3, skq = (tid & 7) * 8;
    int kp = tid & 31, cg = tid >> 5;

    f32x4 acc[2] = {};
    float4 areg0, areg1;
    float4 w00, w10;

    {
        const float* ap = &A[(size_t)(R0 + sr) * DIM + skq];
        areg0 = *(const float4*)&ap[0];  areg1 = *(const float4*)&ap[4];
        const float* wp0 = &Wsrc[(size_t)(2 * kp)     * DIM + C0 + cg * 4];
        const float* wp1 = &Wsrc[(size_t)(2 * kp + 1) * DIM + C0 + cg * 4];
        w00 = *(const float4*)&wp0[0];
        w10 = *(const float4*)&wp1[0];
    }

    for (int ks = 0; ks < 4; ++ks) {
        {
            int i0 = (sr * 64 + skq) ^ ((sr & 7) << 3);
            uint4 hv = make_uint4(hi2(areg0.x, areg0.y), hi2(areg0.z, areg0.w),
                                  hi2(areg1.x, areg1.y), hi2(areg1.z, areg1.w));
            uint4 lv = make_uint4(hi2(trunc_res(areg0.x), trunc_res(areg0.y)),
                                  hi2(trunc_res(areg0.z), trunc_res(areg0.w)),
                                  hi2(trunc_res(areg1.x), trunc_res(areg1.y)),
                                  hi2(trunc_res(areg1.z), trunc_res(areg1.w)));
            *(uint4*)&Ah[i0] = hv;
            *(uint4*)&Al[i0] = lv;
            float a0[4] = {w00.x, w00.y, w00.z, w00.w};
            float a1[4] = {w10.x, w10.y, w10.z, w10.w};
#pragma unroll
            for (int c = 0; c < 4; ++c) {
                int col = cg * 4 + c;
                int idx = (col * 64 + 2 * kp) ^ ((col & 7) << 3);
                *(unsigned*)&Bh[idx] = hi2(a0[c], a1[c]);
                *(unsigned*)&Bl[idx] = hi2(trunc_res(a0[c]), trunc_res(a1[c]));
            }
        }
        __syncthreads();
        if (ks < 3) {
            int K0 = (ks + 1) * 64;
            const float* ap = &A[(size_t)(R0 + sr) * DIM + K0 + skq];
            areg0 = *(const float4*)&ap[0];  areg1 = *(const float4*)&ap[4];
            const float* wp0 = &Wsrc[(size_t)(K0 + 2 * kp)     * DIM + C0 + cg * 4];
            const float* wp1 = &Wsrc[(size_t)(K0 + 2 * kp + 1) * DIM + C0 + cg * 4];
            w00 = *(const float4*)&wp0[0];
            w10 = *(const float4*)&wp1[0];
        }
#pragma unroll
        for (int kk = 0; kk < 2; ++kk) {
            int kb = kk * 32 + l4 * 8;
            short8 ah[2], al[2], bh, bl;
#pragma unroll
            for (int i = 0; i < 2; ++i) {
                int arow = wr * 32 + i * 16 + l15;
                int aidx = (arow * 64 + kb) ^ ((arow & 7) << 3);
                ah[i] = *(const short8*)&Ah[aidx];
                al[i] = *(const short8*)&Al[aidx];
            }
            {
                int bcol = wc * 16 + l15;
                int bidx = (bcol * 64 + kb) ^ ((bcol & 7) << 3);
                bh = *(const short8*)&Bh[bidx];
                bl = *(const short8*)&Bl[bidx];
            }
#pragma unroll
            for (int i = 0; i < 2; ++i) {
                acc[i] = __builtin_amdgcn_mfma_f32_16x16x32_bf16(ah[i], bh, acc[i], 0, 0, 0);
                acc[i] = __builtin_amdgcn_mfma_f32_16x16x32_bf16(ah[i], bl, acc[i], 0, 0, 0);
                acc[i] = __builtin_amdgcn_mfma_f32_16x16x32_bf16(al[i], bh, acc[i], 0, 0, 0);
            }
        }
        __syncthreads();
    }

#pragma unroll
    for (int i = 0; i < 2; ++i) {
        float ev[4];
#pragma unroll
        for (int v = 0; v < 4; ++v) ev[v] = __builtin_amdgcn_exp2f(C2 * acc[i][v]);
        int row = wr * 32 + i * 16 + l4 * 4;
        int col = wc * 16 + l15;
        if (isK) {
#pragma unroll
            for (int v = 0; v < 4; ++v) T[row + v][col] = ev[v];
        } else {
            *(float4*)&T[col][row] = make_float4(ev[0], ev[1], ev[2], ev[3]);
        }
    }
    __syncthreads();
    {
        int r = tid >> 3, q = tid & 7;
        float* dst = isK ? &EK[(size_t)b * DIM * DIM + (size_t)(R0 + r) * DIM + C0 + q * 8]
                         : &EQ[(size_t)b * DIM * DIM + (size_t)(C0 + r) * DIM + R0 + q * 8];
        *(float4*)&dst[0] = *(const float4*)&T[r][q * 8];
        *(float4*)&dst[4] = *(const float4*)&T[r][q * 8 + 4];
    }
}

// ---------------- fused scores + softmax(axis=n) -> attnN hi/lo bf16 [n][m] ----------------
// 512 thr = 8 waves = (4 h-splits x 2 m-groups); MBLK=8 -> q L2 traffic halved.
// Barrier-free main loop + q-prefetch one chunk ahead.
__global__ __launch_bounds__(512, 2) void scores_softmax_kernel(
    const float* __restrict__ EQ, const float* __restrict__ EK,
    const float* __restrict__ Wv,
    ushort_t* __restrict__ ANh, ushort_t* __restrict__ ANl)
{
    int b  = blockIdx.y;
    int M0 = blockIdx.x * 8;
    const float* Qb = EQ + b * DIM * DIM;   // [h][n]
    const float* Kb = EK + b * DIM * DIM;   // [m][h]

    __shared__ __align__(16) float Eks[8][DIM];         // 8 KB
    __shared__ __align__(16) float Ws[DIM];             // 1 KB
    __shared__ __align__(16) float part[3][2][64][16];  // 24 KB

    int tid  = threadIdx.x;
    int w = tid >> 6, lane = tid & 63;
    int hs = w & 3, mg = w >> 2;
    int n0 = lane * 4;

    {   // stage Eks (8 m-rows x 256 h)
        int row = tid >> 6, h4 = (tid & 63) * 4;
        *(float4*)&Eks[row][h4] = *(const float4*)&Kb[(M0 + row) * DIM + h4];
    }
    if (tid < 64) *(float4*)&Ws[tid * 4] = *(const float4*)&Wv[tid * 4];

    float wsum = Wv[lane] + Wv[lane + 64] + Wv[lane + 128] + Wv[lane + 192];
#pragma unroll
    for (int o = 32; o; o >>= 1) wsum += __shfl_xor(wsum, o);
    __syncthreads();

    float acc[4][4] = {};   // [m-row within mg][n]
    const float* qbase = Qb + (hs * 4) * 256 + n0;

    float4 qr[4];
#pragma unroll
    for (int r = 0; r < 4; ++r) qr[r] = *(const float4*)&qbase[r * 256];

    for (int c = 0; c < 16; ++c) {
        float4 qn[4];
        if (c < 15) {
            const float* qc = qbase + (c + 1) * 4096;
#pragma unroll
            for (int r = 0; r < 4; ++r) qn[r] = *(const float4*)&qc[r * 256];
        }
        float4 wv4 = *(const float4*)&Ws[c * 16 + hs * 4];
        float wva[4] = {wv4.x, wv4.y, wv4.z, wv4.w};
        float eka[4][4];
#pragma unroll
        for (int i = 0; i < 4; ++i) {
            float4 e4 = *(const float4*)&Eks[mg * 4 + i][c * 16 + hs * 4];
            eka[i][0] = e4.x; eka[i][1] = e4.y; eka[i][2] = e4.z; eka[i][3] = e4.w;
        }
#pragma unroll
        for (int hh = 0; hh < 2; ++hh) {
            float q0a[4] = {qr[hh * 2].x, qr[hh * 2].y, qr[hh * 2].z, qr[hh * 2].w};
            float q1a[4] = {qr[hh * 2 + 1].x, qr[hh * 2 + 1].y, qr[hh * 2 + 1].z, qr[hh * 2 + 1].w};
            float w0 = wva[hh * 2], w1 = wva[hh * 2 + 1];
#pragma unroll
            for (int i = 0; i < 4; ++i) {
                float e0 = eka[i][hh * 2], e1 = eka[i][hh * 2 + 1];
#pragma unroll
                for (int j = 0; j < 4; ++j) {
                    float d0 = fmaf(q0a[j], e0, 1.0f);
                    float d1 = fmaf(q1a[j], e1, 1.0f);
                    float num = fmaf(w0, d1, w1 * d0);
                    acc[i][j] = fmaf(num, __builtin_amdgcn_rcpf(d0 * d1), acc[i][j]);
                }
            }
        }
        if (c < 15) {
#pragma unroll
            for (int r = 0; r < 4; ++r) qr[r] = qn[r];
        }
    }

    // combine h-splits (per m-group): hs 1..3 deposit, hs 0 reduces + softmax + write
    if (hs) {
#pragma unroll
        for (int i = 0; i < 4; ++i) {
            float4 v = make_float4(acc[i][0], acc[i][1], acc[i][2], acc[i][3]);
            *(float4*)&part[hs - 1][mg][lane][i * 4] = v;
        }
    }
    __syncthreads();
    if (hs == 0) {
#pragma unroll
        for (int p = 0; p < 3; ++p)
#pragma unroll
            for (int i = 0; i < 4; ++i) {
                float4 v = *(const float4*)&part[p][mg][lane][i * 4];
                acc[i][0] += v.x; acc[i][1] += v.y; acc[i][2] += v.z; acc[i][3] += v.w;
            }
        float e[4][4], t[4], ri[4];
#pragma unroll
        for (int i = 0; i < 4; ++i) {
            t[i] = 0.0f;
#pragma unroll
            for (int j = 0; j < 4; ++j) {
                e[i][j] = __builtin_amdgcn_exp2f((wsum - 2.0f * acc[i][j]) * LOG2E);
                t[i] += e[i][j];
            }
        }
#pragma unroll
        for (int o = 32; o; o >>= 1)
#pragma unroll
            for (int i = 0; i < 4; ++i) t[i] += __shfl_xor(t[i], o);
#pragma unroll
        for (int i = 0; i < 4; ++i) ri[i] = __builtin_amdgcn_rcpf(t[i]);
#pragma unroll
        for (int j = 0; j < 4; ++j) {
            float a0 = e[0][j] * ri[0], a1 = e[1][j] * ri[1];
            float a2 = e[2][j] * ri[2], a3 = e[3][j] * ri[3];
            size_t base = ((size_t)b * DIM + n0 + j) * DIM + M0 + mg * 4;
            *(uint2*)&ANh[base] = make_uint2(hi2(a0, a1), hi2(a2, a3));
            *(uint2*)&ANl[base] = make_uint2(hi2(trunc_res(a0), trunc_res(a1)),
                                             hi2(trunc_res(a2), trunc_res(a3)));
        }
    }
}

// ---------------- av (MFMA): 32(n)x64(d) tiles, 256 blocks (full GPU) ----------------
__global__ __launch_bounds__(256) void av_mfma(
    const ushort_t* __restrict__ ANh, const ushort_t* __restrict__ ANl,
    const float* __restrict__ value, float* __restrict__ out)
{
    __shared__ __align__(16) ushort_t Ah[32 * 64], Al[32 * 64], Bh[64 * 64], Bl[64 * 64];
    __shared__ __align__(16) float T[32][68];

    int b = blockIdx.y;
    int x = blockIdx.x;
    int R0 = (x >> 2) * 32, C0 = (x & 3) * 64;
    const ushort_t* Abh = ANh + (size_t)b * DIM * DIM;
    const ushort_t* Abl = ANl + (size_t)b * DIM * DIM;
    const float*    Vb  = value + (size_t)b * DIM * DIM;

    int tid = threadIdx.x;
    int w = tid >> 6, lane = tid & 63;
    int wr = w >> 1, wc = w & 1;
    int l15 = lane & 15, l4 = lane >> 4;
    int sr = tid >> 3, skq = (tid & 7) * 8;
    int kp = tid & 31, cg = tid >> 5;

    f32x4 acc[2] = {};
    uint4 ah0, al0;
    float4 v00, v01, v10, v11;
    {
        size_t aa = (size_t)(R0 + sr) * DIM + skq;
        ah0 = *(const uint4*)&Abh[aa];
        al0 = *(const uint4*)&Abl[aa];
        const float* vp0 = &Vb[(size_t)(2 * kp)     * DIM + C0 + cg * 8];
        const float* vp1 = &Vb[(size_t)(2 * kp + 1) * DIM + C0 + cg * 8];
        v00 = *(const float4*)&vp0[0]; v01 = *(const float4*)&vp0[4];
        v10 = *(const float4*)&vp1[0]; v11 = *(const float4*)&vp1[4];
    }

    for (int ks = 0; ks < 4; ++ks) {
        {
            int i0 = (sr * 64 + skq) ^ ((sr & 7) << 3);
            *(uint4*)&Ah[i0] = ah0;
            *(uint4*)&Al[i0] = al0;
            float a0[8] = {v00.x, v00.y, v00.z, v00.w, v01.x, v01.y, v01.z, v01.w};
            float a1[8] = {v10.x, v10.y, v10.z, v10.w, v11.x, v11.y, v11.z, v11.w};
#pragma unroll
            for (int c = 0; c < 8; ++c) {
                int col = cg * 8 + c;
                int idx = (col * 64 + 2 * kp) ^ ((col & 7) << 3);
                *(unsigned*)&Bh[idx] = hi2(a0[c], a1[c]);
                *(unsigned*)&Bl[idx] = hi2(trunc_res(a0[c]), trunc_res(a1[c]));
            }
        }
        __syncthreads();
        if (ks < 3) {
            int K0 = (ks + 1) * 64;
            size_t aa = (size_t)(R0 + sr) * DIM + K0 + skq;
            ah0 = *(const uint4*)&Abh[aa];
            al0 = *(const uint4*)&Abl[aa];
            const float* vp0 = &Vb[(size_t)(K0 + 2 * kp)     * DIM + C0 + cg * 8];
            const float* vp1 = &Vb[(size_t)(K0 + 2 * kp + 1) * DIM + C0 + cg * 8];
            v00 = *(const float4*)&vp0[0]; v01 = *(const float4*)&vp0[4];
            v10 = *(const float4*)&vp1[0]; v11 = *(const float4*)&vp1[4];
        }
#pragma unroll
        for (int kk = 0; kk < 2; ++kk) {
            int kb = kk * 32 + l4 * 8;
            short8 ah, al, bh[2], bl[2];
            {
                int arow = wr * 16 + l15;
                int aidx = (arow * 64 + kb) ^ ((arow & 7) << 3);
                ah = *(const short8*)&Ah[aidx];
                al = *(const short8*)&Al[aidx];
            }
#pragma unroll
            for (int j = 0; j < 2; ++j) {
                int bcol = wc * 32 + j * 16 + l15;
                int bidx = (bcol * 64 + kb) ^ ((bcol & 7) << 3);
                bh[j] = *(const short8*)&Bh[bidx];
                bl[j] = *(const short8*)&Bl[bidx];
            }
#pragma unroll
            for (int j = 0; j < 2; ++j) {
                acc[j] = __builtin_amdgcn_mfma_f32_16x16x32_bf16(ah, bh[j], acc[j], 0, 0, 0);
                acc[j] = __builtin_amdgcn_mfma_f32_16x16x32_bf16(ah, bl[j], acc[j], 0, 0, 0);
                acc[j] = __builtin_amdgcn_mfma_f32_16x16x32_bf16(al, bh[j], acc[j], 0, 0, 0);
            }
        }
        __syncthreads();
    }

#pragma unroll
    for (int j = 0; j < 2; ++j) {
        int row = wr * 16 + l4 * 4;
        int col = wc * 32 + j * 16 + l15;
#pragma unroll
        for (int v = 0; v < 4; ++v) T[row + v][col] = acc[j][v];
    }
    __syncthreads();
    {
        int r = tid >> 3, q = tid & 7;
        float* dst = &out[((size_t)b * DIM + R0 + r) * DIM + C0 + q * 8];
        *(float4*)&dst[0] = *(const float4*)&T[r][q * 8];
        *(float4*)&dst[4] = *(const float4*)&T[r][q * 8 + 4];
    }
}

extern "C" void kernel_launch(void* const* d_in, const int* in_sizes, int n_in,
                              void* d_out, int out_size, void* d_ws, size_t ws_size,
                              hipStream_t stream)
{
    const float* query = (const float*)d_in[0];
    const float* key   = (const float*)d_in[1];
    const float* value = (const float*)d_in[2];
    const float* Wq    = (const float*)d_in[3];
    const float* Wk    = (const float*)d_in[4];
    const float* Wv    = (const float*)d_in[5];
    float* out = (float*)d_out;

    float* EQ = (float*)d_ws;
    float* EK = EQ + N_B * DIM * DIM;
    ushort_t* us = (ushort_t*)(EK + N_B * DIM * DIM);
    ushort_t* ANh = us; us += N_B * DIM * DIM;
    ushort_t* ANl = us; us += N_B * DIM * DIM;

    proj_mfma            <<<dim3(16, 16), 512, 0, stream>>>(query, key, Wq, Wk, EQ, EK);
    scores_softmax_kernel<<<dim3(32, 8),  512, 0, stream>>>(EQ, EK, Wv, ANh, ANl);
    av_mfma              <<<dim3(32, 8),  256, 0, stream>>>(ANh, ANl, value, out);
}

// Round 20
// 32.959 us; speedup vs baseline: 11.2968x; 1.1697x over previous
//
#include <hip/hip_runtime.h>

#define N_B 8
#define DIM 256

constexpr float C2    = 2.8853900817779268f;   // 2*log2(e)
constexpr float LOG2E = 1.4426950408889634f;

typedef __attribute__((ext_vector_type(8))) short short8;
typedef __attribute__((ext_vector_type(4))) float f32x4;
typedef unsigned short ushort_t;

__device__ __forceinline__ unsigned hi2(float a, float b) {
    return (__float_as_uint(a) >> 16) | (__float_as_uint(b) & 0xFFFF0000u);
}
__device__ __forceinline__ float trunc_res(float a) {
    return a - __uint_as_float(__float_as_uint(a) & 0xFFFF0000u);
}

// ---------------- proj (MFMA, 512 thr = 8 waves, in-kernel W transpose) ----------------
// 1D grid 256; y = bid&15 (XCD-local A panels), x = bid>>4.
__global__ __launch_bounds__(512) void proj_mfma(
    const float* __restrict__ query, const float* __restrict__ key,
    const float* __restrict__ Wq, const float* __restrict__ Wk,
    float* __restrict__ EQ, float* __restrict__ EK)
{
    __shared__ __align__(16) ushort_t Ah[64 * 64], Al[64 * 64], Bh[64 * 64], Bl[64 * 64];
    __shared__ __align__(16) float T[64][68];

    int bid = blockIdx.x;
    int y = bid & 15;                 // shares A panel within XCD
    int x = bid >> 4;
    int b = y >> 1; bool isK = y & 1;
    const float* A    = (isK ? key : query) + b * DIM * DIM;
    const float* Wsrc = isK ? Wk : Wq;

    int R0 = (x >> 2) * 64, C0 = (x & 3) * 64;

    int tid = threadIdx.x;
    int w = tid >> 6, lane = tid & 63;
    int wr = w >> 2, wc = w & 3;
    int l15 = lane & 15, l4 = lane >> 4;

    int sr = tid >> 3, skq = (tid & 7) * 8;
    int kp = tid & 31, cg = tid >> 5;

    f32x4 acc[2] = {};
    float4 areg0, areg1;
    float4 w00, w10;

    {
        const float* ap = &A[(size_t)(R0 + sr) * DIM + skq];
        areg0 = *(const float4*)&ap[0];  areg1 = *(const float4*)&ap[4];
        const float* wp0 = &Wsrc[(size_t)(2 * kp)     * DIM + C0 + cg * 4];
        const float* wp1 = &Wsrc[(size_t)(2 * kp + 1) * DIM + C0 + cg * 4];
        w00 = *(const float4*)&wp0[0];
        w10 = *(const float4*)&wp1[0];
    }

    for (int ks = 0; ks < 4; ++ks) {
        {
            int i0 = (sr * 64 + skq) ^ ((sr & 7) << 3);
            uint4 hv = make_uint4(hi2(areg0.x, areg0.y), hi2(areg0.z, areg0.w),
                                  hi2(areg1.x, areg1.y), hi2(areg1.z, areg1.w));
            uint4 lv = make_uint4(hi2(trunc_res(areg0.x), trunc_res(areg0.y)),
                                  hi2(trunc_res(areg0.z), trunc_res(areg0.w)),
                                  hi2(trunc_res(areg1.x), trunc_res(areg1.y)),
                                  hi2(trunc_res(areg1.z), trunc_res(areg1.w)));
            *(uint4*)&Ah[i0] = hv;
            *(uint4*)&Al[i0] = lv;
            float a0[4] = {w00.x, w00.y, w00.z, w00.w};
            float a1[4] = {w10.x, w10.y, w10.z, w10.w};
#pragma unroll
            for (int c = 0; c < 4; ++c) {
                int col = cg * 4 + c;
                int idx = (col * 64 + 2 * kp) ^ ((col & 7) << 3);
                *(unsigned*)&Bh[idx] = hi2(a0[c], a1[c]);
                *(unsigned*)&Bl[idx] = hi2(trunc_res(a0[c]), trunc_res(a1[c]));
            }
        }
        __syncthreads();
        if (ks < 3) {
            int K0 = (ks + 1) * 64;
            const float* ap = &A[(size_t)(R0 + sr) * DIM + K0 + skq];
            areg0 = *(const float4*)&ap[0];  areg1 = *(const float4*)&ap[4];
            const float* wp0 = &Wsrc[(size_t)(K0 + 2 * kp)     * DIM + C0 + cg * 4];
            const float* wp1 = &Wsrc[(size_t)(K0 + 2 * kp + 1) * DIM + C0 + cg * 4];
            w00 = *(const float4*)&wp0[0];
            w10 = *(const float4*)&wp1[0];
        }
#pragma unroll
        for (int kk = 0; kk < 2; ++kk) {
            int kb = kk * 32 + l4 * 8;
            short8 ah[2], al[2], bh, bl;
#pragma unroll
            for (int i = 0; i < 2; ++i) {
                int arow = wr * 32 + i * 16 + l15;
                int aidx = (arow * 64 + kb) ^ ((arow & 7) << 3);
                ah[i] = *(const short8*)&Ah[aidx];
                al[i] = *(const short8*)&Al[aidx];
            }
            {
                int bcol = wc * 16 + l15;
                int bidx = (bcol * 64 + kb) ^ ((bcol & 7) << 3);
                bh = *(const short8*)&Bh[bidx];
                bl = *(const short8*)&Bl[bidx];
            }
#pragma unroll
            for (int i = 0; i < 2; ++i) {
                acc[i] = __builtin_amdgcn_mfma_f32_16x16x32_bf16(ah[i], bh, acc[i], 0, 0, 0);
                acc[i] = __builtin_amdgcn_mfma_f32_16x16x32_bf16(ah[i], bl, acc[i], 0, 0, 0);
                acc[i] = __builtin_amdgcn_mfma_f32_16x16x32_bf16(al[i], bh, acc[i], 0, 0, 0);
            }
        }
        __syncthreads();
    }

#pragma unroll
    for (int i = 0; i < 2; ++i) {
        float ev[4];
#pragma unroll
        for (int v = 0; v < 4; ++v) ev[v] = __builtin_amdgcn_exp2f(C2 * acc[i][v]);
        int row = wr * 32 + i * 16 + l4 * 4;
        int col = wc * 16 + l15;
        if (isK) {
#pragma unroll
            for (int v = 0; v < 4; ++v) T[row + v][col] = ev[v];
        } else {
            *(float4*)&T[col][row] = make_float4(ev[0], ev[1], ev[2], ev[3]);
        }
    }
    __syncthreads();
    {
        int r = tid >> 3, q = tid & 7;
        float* dst = isK ? &EK[(size_t)b * DIM * DIM + (size_t)(R0 + r) * DIM + C0 + q * 8]
                         : &EQ[(size_t)b * DIM * DIM + (size_t)(C0 + r) * DIM + R0 + q * 8];
        *(float4*)&dst[0] = *(const float4*)&T[r][q * 8];
        *(float4*)&dst[4] = *(const float4*)&T[r][q * 8 + 4];
    }
}

// ---------------- fused scores + softmax(axis=n) -> attnN hi bf16 [n][m] (hi only) ----------------
// 1D grid 256; b = bid&7 (one batch per XCD -> EQ/EK XCD-local), M0 from bid>>3.
__global__ __launch_bounds__(512, 2) void scores_softmax_kernel(
    const float* __restrict__ EQ, const float* __restrict__ EK,
    const float* __restrict__ Wv, ushort_t* __restrict__ ANh)
{
    int bid = blockIdx.x;
    int b  = bid & 7;
    int M0 = (bid >> 3) * 8;
    const float* Qb = EQ + b * DIM * DIM;   // [h][n]
    const float* Kb = EK + b * DIM * DIM;   // [m][h]

    __shared__ __align__(16) float Eks[8][DIM];
    __shared__ __align__(16) float Ws[DIM];
    __shared__ __align__(16) float part[3][2][64][16];

    int tid  = threadIdx.x;
    int w = tid >> 6, lane = tid & 63;
    int hs = w & 3, mg = w >> 2;
    int n0 = lane * 4;

    {
        int row = tid >> 6, h4 = (tid & 63) * 4;
        *(float4*)&Eks[row][h4] = *(const float4*)&Kb[(M0 + row) * DIM + h4];
    }
    if (tid < 64) *(float4*)&Ws[tid * 4] = *(const float4*)&Wv[tid * 4];

    float wsum = Wv[lane] + Wv[lane + 64] + Wv[lane + 128] + Wv[lane + 192];
#pragma unroll
    for (int o = 32; o; o >>= 1) wsum += __shfl_xor(wsum, o);
    __syncthreads();

    float acc[4][4] = {};
    const float* qbase = Qb + (hs * 4) * 256 + n0;

    float4 qr[4];
#pragma unroll
    for (int r = 0; r < 4; ++r) qr[r] = *(const float4*)&qbase[r * 256];

    for (int c = 0; c < 16; ++c) {
        float4 qn[4];
        if (c < 15) {
            const float* qc = qbase + (c + 1) * 4096;
#pragma unroll
            for (int r = 0; r < 4; ++r) qn[r] = *(const float4*)&qc[r * 256];
        }
        float4 wv4 = *(const float4*)&Ws[c * 16 + hs * 4];
        float wva[4] = {wv4.x, wv4.y, wv4.z, wv4.w};
        float eka[4][4];
#pragma unroll
        for (int i = 0; i < 4; ++i) {
            float4 e4 = *(const float4*)&Eks[mg * 4 + i][c * 16 + hs * 4];
            eka[i][0] = e4.x; eka[i][1] = e4.y; eka[i][2] = e4.z; eka[i][3] = e4.w;
        }
#pragma unroll
        for (int hh = 0; hh < 2; ++hh) {
            float q0a[4] = {qr[hh * 2].x, qr[hh * 2].y, qr[hh * 2].z, qr[hh * 2].w};
            float q1a[4] = {qr[hh * 2 + 1].x, qr[hh * 2 + 1].y, qr[hh * 2 + 1].z, qr[hh * 2 + 1].w};
            float w0 = wva[hh * 2], w1 = wva[hh * 2 + 1];
#pragma unroll
            for (int i = 0; i < 4; ++i) {
                float e0 = eka[i][hh * 2], e1 = eka[i][hh * 2 + 1];
#pragma unroll
                for (int j = 0; j < 4; ++j) {
                    float d0 = fmaf(q0a[j], e0, 1.0f);
                    float d1 = fmaf(q1a[j], e1, 1.0f);
                    float num = fmaf(w0, d1, w1 * d0);
                    acc[i][j] = fmaf(num, __builtin_amdgcn_rcpf(d0 * d1), acc[i][j]);
                }
            }
        }
        if (c < 15) {
#pragma unroll
            for (int r = 0; r < 4; ++r) qr[r] = qn[r];
        }
    }

    if (hs) {
#pragma unroll
        for (int i = 0; i < 4; ++i) {
            float4 v = make_float4(acc[i][0], acc[i][1], acc[i][2], acc[i][3]);
            *(float4*)&part[hs - 1][mg][lane][i * 4] = v;
        }
    }
    __syncthreads();
    if (hs == 0) {
#pragma unroll
        for (int p = 0; p < 3; ++p)
#pragma unroll
            for (int i = 0; i < 4; ++i) {
                float4 v = *(const float4*)&part[p][mg][lane][i * 4];
                acc[i][0] += v.x; acc[i][1] += v.y; acc[i][2] += v.z; acc[i][3] += v.w;
            }
        float e[4][4], t[4], ri[4];
#pragma unroll
        for (int i = 0; i < 4; ++i) {
            t[i] = 0.0f;
#pragma unroll
            for (int j = 0; j < 4; ++j) {
                e[i][j] = __builtin_amdgcn_exp2f((wsum - 2.0f * acc[i][j]) * LOG2E);
                t[i] += e[i][j];
            }
        }
#pragma unroll
        for (int o = 32; o; o >>= 1)
#pragma unroll
            for (int i = 0; i < 4; ++i) t[i] += __shfl_xor(t[i], o);
#pragma unroll
        for (int i = 0; i < 4; ++i) ri[i] = __builtin_amdgcn_rcpf(t[i]);
#pragma unroll
        for (int j = 0; j < 4; ++j) {
            float a0 = e[0][j] * ri[0], a1 = e[1][j] * ri[1];
            float a2 = e[2][j] * ri[2], a3 = e[3][j] * ri[3];
            size_t base = ((size_t)b * DIM + n0 + j) * DIM + M0 + mg * 4;
            *(uint2*)&ANh[base] = make_uint2(hi2(a0, a1), hi2(a2, a3));
        }
    }
}

// ---------------- av (MFMA): 32(n)x64(d) tiles; attn hi-only (2 MFMAs/step) ----------------
// 1D grid 256; b = bid&7 (AN[b], V[b] XCD-local), x = bid>>3.
__global__ __launch_bounds__(256) void av_mfma(
    const ushort_t* __restrict__ ANh,
    const float* __restrict__ value, float* __restrict__ out)
{
    __shared__ __align__(16) ushort_t Ah[32 * 64], Bh[64 * 64], Bl[64 * 64];
    __shared__ __align__(16) float T[32][68];

    int bid = blockIdx.x;
    int b = bid & 7;
    int x = bid >> 3;
    int R0 = (x >> 2) * 32, C0 = (x & 3) * 64;
    const ushort_t* Abh = ANh + (size_t)b * DIM * DIM;
    const float*    Vb  = value + (size_t)b * DIM * DIM;

    int tid = threadIdx.x;
    int w = tid >> 6, lane = tid & 63;
    int wr = w >> 1, wc = w & 1;
    int l15 = lane & 15, l4 = lane >> 4;
    int sr = tid >> 3, skq = (tid & 7) * 8;
    int kp = tid & 31, cg = tid >> 5;

    f32x4 acc[2] = {};
    uint4 ah0;
    float4 v00, v01, v10, v11;
    {
        size_t aa = (size_t)(R0 + sr) * DIM + skq;
        ah0 = *(const uint4*)&Abh[aa];
        const float* vp0 = &Vb[(size_t)(2 * kp)     * DIM + C0 + cg * 8];
        const float* vp1 = &Vb[(size_t)(2 * kp + 1) * DIM + C0 + cg * 8];
        v00 = *(const float4*)&vp0[0]; v01 = *(const float4*)&vp0[4];
        v10 = *(const float4*)&vp1[0]; v11 = *(const float4*)&vp1[4];
    }

    for (int ks = 0; ks < 4; ++ks) {
        {
            int i0 = (sr * 64 + skq) ^ ((sr & 7) << 3);
            *(uint4*)&Ah[i0] = ah0;
            float a0[8] = {v00.x, v00.y, v00.z, v00.w, v01.x, v01.y, v01.z, v01.w};
            float a1[8] = {v10.x, v10.y, v10.z, v10.w, v11.x, v11.y, v11.z, v11.w};
#pragma unroll
            for (int c = 0; c < 8; ++c) {
                int col = cg * 8 + c;
                int idx = (col * 64 + 2 * kp) ^ ((col & 7) << 3);
                *(unsigned*)&Bh[idx] = hi2(a0[c], a1[c]);
                *(unsigned*)&Bl[idx] = hi2(trunc_res(a0[c]), trunc_res(a1[c]));
            }
        }
        __syncthreads();
        if (ks < 3) {
            int K0 = (ks + 1) * 64;
            size_t aa = (size_t)(R0 + sr) * DIM + K0 + skq;
            ah0 = *(const uint4*)&Abh[aa];
            const float* vp0 = &Vb[(size_t)(K0 + 2 * kp)     * DIM + C0 + cg * 8];
            const float* vp1 = &Vb[(size_t)(K0 + 2 * kp + 1) * DIM + C0 + cg * 8];
            v00 = *(const float4*)&vp0[0]; v01 = *(const float4*)&vp0[4];
            v10 = *(const float4*)&vp1[0]; v11 = *(const float4*)&vp1[4];
        }
#pragma unroll
        for (int kk = 0; kk < 2; ++kk) {
            int kb = kk * 32 + l4 * 8;
            short8 ah, bh[2], bl[2];
            {
                int arow = wr * 16 + l15;
                int aidx = (arow * 64 + kb) ^ ((arow & 7) << 3);
                ah = *(const short8*)&Ah[aidx];
            }
#pragma unroll
            for (int j = 0; j < 2; ++j) {
                int bcol = wc * 32 + j * 16 + l15;
                int bidx = (bcol * 64 + kb) ^ ((bcol & 7) << 3);
                bh[j] = *(const short8*)&Bh[bidx];
                bl[j] = *(const short8*)&Bl[bidx];
            }
#pragma unroll
            for (int j = 0; j < 2; ++j) {
                acc[j] = __builtin_amdgcn_mfma_f32_16x16x32_bf16(ah, bh[j], acc[j], 0, 0, 0);
                acc[j] = __builtin_amdgcn_mfma_f32_16x16x32_bf16(ah, bl[j], acc[j], 0, 0, 0);
            }
        }
        __syncthreads();
    }

#pragma unroll
    for (int j = 0; j < 2; ++j) {
        int row = wr * 16 + l4 * 4;
        int col = wc * 32 + j * 16 + l15;
#pragma unroll
        for (int v = 0; v < 4; ++v) T[row + v][col] = acc[j][v];
    }
    __syncthreads();
    {
        int r = tid >> 3, q = tid & 7;
        float* dst = &out[((size_t)b * DIM + R0 + r) * DIM + C0 + q * 8];
        *(float4*)&dst[0] = *(const float4*)&T[r][q * 8];
        *(float4*)&dst[4] = *(const float4*)&T[r][q * 8 + 4];
    }
}

extern "C" void kernel_launch(void* const* d_in, const int* in_sizes, int n_in,
                              void* d_out, int out_size, void* d_ws, size_t ws_size,
                              hipStream_t stream)
{
    const float* query = (const float*)d_in[0];
    const float* key   = (const float*)d_in[1];
    const float* value = (const float*)d_in[2];
    const float* Wq    = (const float*)d_in[3];
    const float* Wk    = (const float*)d_in[4];
    const float* Wv    = (const float*)d_in[5];
    float* out = (float*)d_out;

    float* EQ = (float*)d_ws;
    float* EK = EQ + N_B * DIM * DIM;
    ushort_t* ANh = (ushort_t*)(EK + N_B * DIM * DIM);

    proj_mfma            <<<256, 512, 0, stream>>>(query, key, Wq, Wk, EQ, EK);
    scores_softmax_kernel<<<256, 512, 0, stream>>>(EQ, EK, Wv, ANh);
    av_mfma              <<<256, 256, 0, stream>>>(ANh, value, out);
}

// Round 21
// 32.189 us; speedup vs baseline: 11.5671x; 1.0239x over previous
//
#include <hip/hip_runtime.h>

#define N_B 8
#define DIM 256

constexpr float C2    = 2.8853900817779268f;   // 2*log2(e)
constexpr float LOG2E = 1.4426950408889634f;

typedef __attribute__((ext_vector_type(8))) short short8;
typedef __attribute__((ext_vector_type(4))) float f32x4;
typedef unsigned short ushort_t;

__device__ __forceinline__ unsigned hi2(float a, float b) {
    return (__float_as_uint(a) >> 16) | (__float_as_uint(b) & 0xFFFF0000u);
}
__device__ __forceinline__ float trunc_res(float a) {
    return a - __uint_as_float(__float_as_uint(a) & 0xFFFF0000u);
}

// ---------------- proj (MFMA, 512 thr = 8 waves, in-kernel W transpose) ----------------
__global__ __launch_bounds__(512) void proj_mfma(
    const float* __restrict__ query, const float* __restrict__ key,
    const float* __restrict__ Wq, const float* __restrict__ Wk,
    float* __restrict__ EQ, float* __restrict__ EK)
{
    __shared__ __align__(16) ushort_t Ah[64 * 64], Al[64 * 64], Bh[64 * 64], Bl[64 * 64];
    __shared__ __align__(16) float T[64][68];

    int bid = blockIdx.x;
    int y = bid & 15;
    int x = bid >> 4;
    int b = y >> 1; bool isK = y & 1;
    const float* A    = (isK ? key : query) + b * DIM * DIM;
    const float* Wsrc = isK ? Wk : Wq;

    int R0 = (x >> 2) * 64, C0 = (x & 3) * 64;

    int tid = threadIdx.x;
    int w = tid >> 6, lane = tid & 63;
    int wr = w >> 2, wc = w & 3;
    int l15 = lane & 15, l4 = lane >> 4;

    int sr = tid >> 3, skq = (tid & 7) * 8;
    int kp = tid & 31, cg = tid >> 5;

    f32x4 acc[2] = {};
    float4 areg0, areg1;
    float4 w00, w10;

    {
        const float* ap = &A[(size_t)(R0 + sr) * DIM + skq];
        areg0 = *(const float4*)&ap[0];  areg1 = *(const float4*)&ap[4];
        const float* wp0 = &Wsrc[(size_t)(2 * kp)     * DIM + C0 + cg * 4];
        const float* wp1 = &Wsrc[(size_t)(2 * kp + 1) * DIM + C0 + cg * 4];
        w00 = *(const float4*)&wp0[0];
        w10 = *(const float4*)&wp1[0];
    }

    for (int ks = 0; ks < 4; ++ks) {
        {
            int i0 = (sr * 64 + skq) ^ ((sr & 7) << 3);
            uint4 hv = make_uint4(hi2(areg0.x, areg0.y), hi2(areg0.z, areg0.w),
                                  hi2(areg1.x, areg1.y), hi2(areg1.z, areg1.w));
            uint4 lv = make_uint4(hi2(trunc_res(areg0.x), trunc_res(areg0.y)),
                                  hi2(trunc_res(areg0.z), trunc_res(areg0.w)),
                                  hi2(trunc_res(areg1.x), trunc_res(areg1.y)),
                                  hi2(trunc_res(areg1.z), trunc_res(areg1.w)));
            *(uint4*)&Ah[i0] = hv;
            *(uint4*)&Al[i0] = lv;
            float a0[4] = {w00.x, w00.y, w00.z, w00.w};
            float a1[4] = {w10.x, w10.y, w10.z, w10.w};
#pragma unroll
            for (int c = 0; c < 4; ++c) {
                int col = cg * 4 + c;
                int idx = (col * 64 + 2 * kp) ^ ((col & 7) << 3);
                *(unsigned*)&Bh[idx] = hi2(a0[c], a1[c]);
                *(unsigned*)&Bl[idx] = hi2(trunc_res(a0[c]), trunc_res(a1[c]));
            }
        }
        __syncthreads();
        if (ks < 3) {
            int K0 = (ks + 1) * 64;
            const float* ap = &A[(size_t)(R0 + sr) * DIM + K0 + skq];
            areg0 = *(const float4*)&ap[0];  areg1 = *(const float4*)&ap[4];
            const float* wp0 = &Wsrc[(size_t)(K0 + 2 * kp)     * DIM + C0 + cg * 4];
            const float* wp1 = &Wsrc[(size_t)(K0 + 2 * kp + 1) * DIM + C0 + cg * 4];
            w00 = *(const float4*)&wp0[0];
            w10 = *(const float4*)&wp1[0];
        }
#pragma unroll
        for (int kk = 0; kk < 2; ++kk) {
            int kb = kk * 32 + l4 * 8;
            short8 ah[2], al[2], bh, bl;
#pragma unroll
            for (int i = 0; i < 2; ++i) {
                int arow = wr * 32 + i * 16 + l15;
                int aidx = (arow * 64 + kb) ^ ((arow & 7) << 3);
                ah[i] = *(const short8*)&Ah[aidx];
                al[i] = *(const short8*)&Al[aidx];
            }
            {
                int bcol = wc * 16 + l15;
                int bidx = (bcol * 64 + kb) ^ ((bcol & 7) << 3);
                bh = *(const short8*)&Bh[bidx];
                bl = *(const short8*)&Bl[bidx];
            }
#pragma unroll
            for (int i = 0; i < 2; ++i) {
                acc[i] = __builtin_amdgcn_mfma_f32_16x16x32_bf16(ah[i], bh, acc[i], 0, 0, 0);
                acc[i] = __builtin_amdgcn_mfma_f32_16x16x32_bf16(ah[i], bl, acc[i], 0, 0, 0);
                acc[i] = __builtin_amdgcn_mfma_f32_16x16x32_bf16(al[i], bh, acc[i], 0, 0, 0);
            }
        }
        __syncthreads();
    }

#pragma unroll
    for (int i = 0; i < 2; ++i) {
        float ev[4];
#pragma unroll
        for (int v = 0; v < 4; ++v) ev[v] = __builtin_amdgcn_exp2f(C2 * acc[i][v]);
        int row = wr * 32 + i * 16 + l4 * 4;
        int col = wc * 16 + l15;
        if (isK) {
#pragma unroll
            for (int v = 0; v < 4; ++v) T[row + v][col] = ev[v];
        } else {
            *(float4*)&T[col][row] = make_float4(ev[0], ev[1], ev[2], ev[3]);
        }
    }
    __syncthreads();
    {
        int r = tid >> 3, q = tid & 7;
        float* dst = isK ? &EK[(size_t)b * DIM * DIM + (size_t)(R0 + r) * DIM + C0 + q * 8]
                         : &EQ[(size_t)b * DIM * DIM + (size_t)(C0 + r) * DIM + R0 + q * 8];
        *(float4*)&dst[0] = *(const float4*)&T[r][q * 8];
        *(float4*)&dst[4] = *(const float4*)&T[r][q * 8 + 4];
    }
}

// ---------------- fused scores + softmax(axis=n) -> attnN hi bf16 [n][m] ----------------
// 1D grid 512 (b = bid&7 -> XCD-local EQ/EK); MBLK=4, 512 thr = 8 waves = 4 hs x 2 mg
// (mg owns 2 m-rows) -> 2 blocks/CU = 4 waves/SIMD.
__global__ __launch_bounds__(512, 2) void scores_softmax_kernel(
    const float* __restrict__ EQ, const float* __restrict__ EK,
    const float* __restrict__ Wv, ushort_t* __restrict__ ANh)
{
    int bid = blockIdx.x;
    int b  = bid & 7;
    int M0 = (bid >> 3) * 4;
    const float* Qb = EQ + b * DIM * DIM;   // [h][n]
    const float* Kb = EK + b * DIM * DIM;   // [m][h]

    __shared__ __align__(16) float Eks[4][DIM];        // 4 KB
    __shared__ __align__(16) float Ws[DIM];            // 1 KB
    __shared__ __align__(16) float part[3][2][64][8];  // 12 KB

    int tid  = threadIdx.x;
    int w = tid >> 6, lane = tid & 63;
    int hs = w & 3, mg = w >> 2;
    int n0 = lane * 4;

    {   // stage Eks (4 m-rows x 256 h)
        int row = tid >> 7, h2 = (tid & 127) * 2;
        *(float2*)&Eks[row][h2] = *(const float2*)&Kb[(M0 + row) * DIM + h2];
    }
    if (tid < 64) *(float4*)&Ws[tid * 4] = *(const float4*)&Wv[tid * 4];

    float wsum = Wv[lane] + Wv[lane + 64] + Wv[lane + 128] + Wv[lane + 192];
#pragma unroll
    for (int o = 32; o; o >>= 1) wsum += __shfl_xor(wsum, o);
    __syncthreads();

    float acc[2][4] = {};   // [m-row within mg][n]
    const float* qbase = Qb + (hs * 4) * 256 + n0;

    float4 qr[4];
#pragma unroll
    for (int r = 0; r < 4; ++r) qr[r] = *(const float4*)&qbase[r * 256];

    for (int c = 0; c < 16; ++c) {
        float4 qn[4];
        if (c < 15) {
            const float* qc = qbase + (c + 1) * 4096;
#pragma unroll
            for (int r = 0; r < 4; ++r) qn[r] = *(const float4*)&qc[r * 256];
        }
        float4 wv4 = *(const float4*)&Ws[c * 16 + hs * 4];
        float wva[4] = {wv4.x, wv4.y, wv4.z, wv4.w};
        float eka[2][4];
#pragma unroll
        for (int i = 0; i < 2; ++i) {
            float4 e4 = *(const float4*)&Eks[mg * 2 + i][c * 16 + hs * 4];
            eka[i][0] = e4.x; eka[i][1] = e4.y; eka[i][2] = e4.z; eka[i][3] = e4.w;
        }
#pragma unroll
        for (int hh = 0; hh < 2; ++hh) {
            float q0a[4] = {qr[hh * 2].x, qr[hh * 2].y, qr[hh * 2].z, qr[hh * 2].w};
            float q1a[4] = {qr[hh * 2 + 1].x, qr[hh * 2 + 1].y, qr[hh * 2 + 1].z, qr[hh * 2 + 1].w};
            float w0 = wva[hh * 2], w1 = wva[hh * 2 + 1];
#pragma unroll
            for (int i = 0; i < 2; ++i) {
                float e0 = eka[i][hh * 2], e1 = eka[i][hh * 2 + 1];
#pragma unroll
                for (int j = 0; j < 4; ++j) {
                    float d0 = fmaf(q0a[j], e0, 1.0f);
                    float d1 = fmaf(q1a[j], e1, 1.0f);
                    float num = fmaf(w0, d1, w1 * d0);
                    acc[i][j] = fmaf(num, __builtin_amdgcn_rcpf(d0 * d1), acc[i][j]);
                }
            }
        }
        if (c < 15) {
#pragma unroll
            for (int r = 0; r < 4; ++r) qr[r] = qn[r];
        }
    }

    // combine h-splits: hs 1..3 deposit, hs 0 reduces + softmax + write
    if (hs) {
#pragma unroll
        for (int i = 0; i < 2; ++i) {
            float4 v = make_float4(acc[i][0], acc[i][1], acc[i][2], acc[i][3]);
            *(float4*)&part[hs - 1][mg][lane][i * 4] = v;
        }
    }
    __syncthreads();
    if (hs == 0) {
#pragma unroll
        for (int p = 0; p < 3; ++p)
#pragma unroll
            for (int i = 0; i < 2; ++i) {
                float4 v = *(const float4*)&part[p][mg][lane][i * 4];
                acc[i][0] += v.x; acc[i][1] += v.y; acc[i][2] += v.z; acc[i][3] += v.w;
            }
        float e[2][4], t[2];
#pragma unroll
        for (int i = 0; i < 2; ++i) {
            t[i] = 0.0f;
#pragma unroll
            for (int j = 0; j < 4; ++j) {
                e[i][j] = __builtin_amdgcn_exp2f((wsum - 2.0f * acc[i][j]) * LOG2E);
                t[i] += e[i][j];
            }
        }
#pragma unroll
        for (int o = 32; o; o >>= 1) { t[0] += __shfl_xor(t[0], o); t[1] += __shfl_xor(t[1], o); }
        float r0 = __builtin_amdgcn_rcpf(t[0]);
        float r1 = __builtin_amdgcn_rcpf(t[1]);
        int mcol = M0 + mg * 2;
#pragma unroll
        for (int j = 0; j < 4; ++j) {
            float a0 = e[0][j] * r0, a1 = e[1][j] * r1;
            *(unsigned*)&ANh[((size_t)b * DIM + n0 + j) * DIM + mcol] = hi2(a0, a1);
        }
    }
}

// ---------------- av (MFMA): 32(n)x32(d) tiles, grid 512 (2 blocks/CU) ----------------
__global__ __launch_bounds__(256) void av_mfma(
    const ushort_t* __restrict__ ANh,
    const float* __restrict__ value, float* __restrict__ out)
{
    __shared__ __align__(16) ushort_t Ah[32 * 64], Bh[32 * 64], Bl[32 * 64];
    __shared__ __align__(16) float T[32][36];

    int bid = blockIdx.x;
    int b = bid & 7;
    int x = bid >> 3;                         // 0..63
    int R0 = (x >> 3) * 32, C0 = (x & 7) * 32;   // 8 n-tiles x 8 d-tiles
    const ushort_t* Abh = ANh + (size_t)b * DIM * DIM;
    const float*    Vb  = value + (size_t)b * DIM * DIM;

    int tid = threadIdx.x;
    int w = tid >> 6, lane = tid & 63;
    int wr = w >> 1, wc = w & 1;              // 16n x 16d per wave
    int l15 = lane & 15, l4 = lane >> 4;
    int sr = tid >> 3, skq = (tid & 7) * 8;   // A staging: n-row 0..31, m-octet
    int kp = tid & 31, cg = tid >> 5;         // V staging: m-pair, d-quad (cg 0..7)

    f32x4 acc[2] = {};                        // 2 kk-independent? no: [wc half] -> single; use [1]
    f32x4 a0acc = {};
    uint4 ah0;
    float4 v00, v10;
    {
        size_t aa = (size_t)(R0 + sr) * DIM + skq;
        ah0 = *(const uint4*)&Abh[aa];
        const float* vp0 = &Vb[(size_t)(2 * kp)     * DIM + C0 + cg * 4];
        const float* vp1 = &Vb[(size_t)(2 * kp + 1) * DIM + C0 + cg * 4];
        v00 = *(const float4*)&vp0[0];
        v10 = *(const float4*)&vp1[0];
    }

    for (int ks = 0; ks < 4; ++ks) {
        {
            int i0 = (sr * 64 + skq) ^ ((sr & 7) << 3);
            *(uint4*)&Ah[i0] = ah0;
            float a0[4] = {v00.x, v00.y, v00.z, v00.w};
            float a1[4] = {v10.x, v10.y, v10.z, v10.w};
#pragma unroll
            for (int c = 0; c < 4; ++c) {
                int col = cg * 4 + c;
                int idx = (col * 64 + 2 * kp) ^ ((col & 7) << 3);
                *(unsigned*)&Bh[idx] = hi2(a0[c], a1[c]);
                *(unsigned*)&Bl[idx] = hi2(trunc_res(a0[c]), trunc_res(a1[c]));
            }
        }
        __syncthreads();
        if (ks < 3) {
            int K0 = (ks + 1) * 64;
            size_t aa = (size_t)(R0 + sr) * DIM + K0 + skq;
            ah0 = *(const uint4*)&Abh[aa];
            const float* vp0 = &Vb[(size_t)(K0 + 2 * kp)     * DIM + C0 + cg * 4];
            const float* vp1 = &Vb[(size_t)(K0 + 2 * kp + 1) * DIM + C0 + cg * 4];
            v00 = *(const float4*)&vp0[0];
            v10 = *(const float4*)&vp1[0];
        }
#pragma unroll
        for (int kk = 0; kk < 2; ++kk) {
            int kb = kk * 32 + l4 * 8;
            short8 ah, bh, bl;
            {
                int arow = wr * 16 + l15;
                int aidx = (arow * 64 + kb) ^ ((arow & 7) << 3);
                ah = *(const short8*)&Ah[aidx];
            }
            {
                int bcol = wc * 16 + l15;
                int bidx = (bcol * 64 + kb) ^ ((bcol & 7) << 3);
                bh = *(const short8*)&Bh[bidx];
                bl = *(const short8*)&Bl[bidx];
            }
            a0acc = __builtin_amdgcn_mfma_f32_16x16x32_bf16(ah, bh, a0acc, 0, 0, 0);
            a0acc = __builtin_amdgcn_mfma_f32_16x16x32_bf16(ah, bl, a0acc, 0, 0, 0);
        }
        __syncthreads();
    }

    {
        int row = wr * 16 + l4 * 4;
        int col = wc * 16 + l15;
#pragma unroll
        for (int v = 0; v < 4; ++v) T[row + v][col] = a0acc[v];
    }
    __syncthreads();
    {
        int r = tid >> 3, q = tid & 7;        // r 0..31, q 0..7 -> 4 floats
        float* dst = &out[((size_t)b * DIM + R0 + r) * DIM + C0 + q * 4];
        *(float4*)&dst[0] = *(const float4*)&T[r][q * 4];
    }
}

extern "C" void kernel_launch(void* const* d_in, const int* in_sizes, int n_in,
                              void* d_out, int out_size, void* d_ws, size_t ws_size,
                              hipStream_t stream)
{
    const float* query = (const float*)d_in[0];
    const float* key   = (const float*)d_in[1];
    const float* value = (const float*)d_in[2];
    const float* Wq    = (const float*)d_in[3];
    const float* Wk    = (const float*)d_in[4];
    const float* Wv    = (const float*)d_in[5];
    float* out = (float*)d_out;

    float* EQ = (float*)d_ws;
    float* EK = EQ + N_B * DIM * DIM;
    ushort_t* ANh = (ushort_t*)(EK + N_B * DIM * DIM);

    proj_mfma            <<<256, 512, 0, stream>>>(query, key, Wq, Wk, EQ, EK);
    scores_softmax_kernel<<<512, 512, 0, stream>>>(EQ, EK, Wv, ANh);
    av_mfma              <<<512, 256, 0, stream>>>(ANh, value, out);
}